// Round 1
// baseline (217.998 us; speedup 1.0000x reference)
//
#include <hip/hip_runtime.h>
#include <hip/hip_bf16.h>

#define CDIM   64
#define HWDIM  4096
#define NCODES 1024
#define NELEM  8388608   // 32*64*64*64 = N*C

typedef short bf16x8 __attribute__((ext_vector_type(8)));
typedef float f32x4  __attribute__((ext_vector_type(4)));

__device__ __forceinline__ unsigned short f2bf(float f) {
    union { float f; unsigned u; } v; v.f = f;
    unsigned r = v.u + 0x7fffu + ((v.u >> 16) & 1u);   // round-to-nearest-even
    return (unsigned short)(r >> 16);
}

// Precompute bf16 codebook + ||e_k||^2 bias; zero loss accumulator.
__global__ void vq_prep(const float* __restrict__ E,
                        unsigned short* __restrict__ Eb,
                        float* __restrict__ bias,
                        float* __restrict__ lossAcc) {
    int t = blockIdx.x * blockDim.x + threadIdx.x;   // one thread per code
    if (t == 0) lossAcc[0] = 0.f;
    if (t < NCODES) {
        float s = 0.f;
        #pragma unroll 8
        for (int c = 0; c < CDIM; ++c) {
            float v = E[t * CDIM + c];
            Eb[t * CDIM + c] = f2bf(v);
            s += v * v;
        }
        bias[t] = s;
    }
}

// One wave = 16 rows x all 1024 codes. block = 4 waves = 64 rows.
__global__ __launch_bounds__(256)
void vq_main(const float* __restrict__ z,
             const float* __restrict__ E,
             const unsigned short* __restrict__ Eb,
             const float* __restrict__ bias,
             float* __restrict__ out,
             float* __restrict__ lossAcc) {
    const int lane = threadIdx.x & 63;
    const int wave = threadIdx.x >> 6;
    const int lrow = lane & 15;    // row within the wave's 16-row tile (A frag)
    const int lgrp = lane >> 4;    // k-group 0..3

    const int n0 = blockIdx.x * 64 + wave * 16;   // first flat row (b*4096+hw)
    const int b  = n0 >> 12;
    const int hw = n0 & 4095;
    const float* zb   = z   + (size_t)b * (CDIM * HWDIM);
    float*       outb = out + (size_t)b * (CDIM * HWDIM);

    // A fragment: lane holds A[row=lrow][k=32*s+8*lgrp+j], j=0..7, s=0..1.
    // z layout: zb[c*HWDIM + hw + row]  (c is the K dim). Keep fp32 for loss.
    float  zf[16];
    bf16x8 afrag[2];
    #pragma unroll
    for (int s = 0; s < 2; ++s) {
        #pragma unroll
        for (int j = 0; j < 8; ++j) {
            int c = 32 * s + 8 * lgrp + j;
            float v = zb[c * HWDIM + hw + lrow];
            zf[8 * s + j] = v;
            afrag[s][j] = (short)f2bf(v);
        }
    }

    float runmin[4] = {1e38f, 1e38f, 1e38f, 1e38f};
    int   runidx[4] = {0, 0, 0, 0};

    for (int kt = 0; kt < 64; ++kt) {
        const int code = kt * 16 + lrow;   // B col = lane&15
        // B fragment: lane holds B[k=32*s+8*lgrp+j][col=code] = Eb[code][k]
        bf16x8 b0 = *(const bf16x8*)(Eb + code * CDIM      + 8 * lgrp);
        bf16x8 b1 = *(const bf16x8*)(Eb + code * CDIM + 32 + 8 * lgrp);
        f32x4 acc = {0.f, 0.f, 0.f, 0.f};
        acc = __builtin_amdgcn_mfma_f32_16x16x32_bf16(afrag[0], b0, acc, 0, 0, 0);
        acc = __builtin_amdgcn_mfma_f32_16x16x32_bf16(afrag[1], b1, acc, 0, 0, 0);
        // C/D layout: col = lane&15 (code), row = 4*lgrp + r  [m89-verified]
        const float bv = bias[code];
        #pragma unroll
        for (int r = 0; r < 4; ++r) {
            float d = fmaf(acc[r], -2.f, bv);   // ||e||^2 - 2 z.e
            if (d < runmin[r]) { runmin[r] = d; runidx[r] = code; }
        }
    }

    // reduce across the 16 code-columns (lanes differing in lrow bits)
    #pragma unroll
    for (int m = 1; m <= 8; m <<= 1) {
        #pragma unroll
        for (int r = 0; r < 4; ++r) {
            float om = __shfl_xor(runmin[r], m, 64);
            int   oi = __shfl_xor(runidx[r], m, 64);
            if (om < runmin[r] || (om == runmin[r] && oi < runidx[r])) {
                runmin[r] = om; runidx[r] = oi;
            }
        }
    }

    // publish per-row argmin: lane group lgrp holds rows 4*lgrp+r
    __shared__ int sidx[4][16];
    if (lrow == 0) {
        #pragma unroll
        for (int r = 0; r < 4; ++r) sidx[wave][4 * lgrp + r] = runidx[r];
    }
    __syncthreads();

    // fused epilogue: gather fp32 codebook row, write transposed out, exact loss
    const int idxr = sidx[wave][lrow];    // argmin for row lrow
    float ls = 0.f;
    #pragma unroll
    for (int s = 0; s < 2; ++s) {
        #pragma unroll
        for (int j = 0; j < 8; ++j) {
            int c = 32 * s + 8 * lgrp + j;
            float q = E[idxr * CDIM + c];
            outb[c * HWDIM + hw + lrow] = q;
            float dz = q - zf[8 * s + j];
            ls = fmaf(dz, dz, ls);
        }
    }
    #pragma unroll
    for (int m = 32; m >= 1; m >>= 1) ls += __shfl_xor(ls, m, 64);
    if (lane == 0) atomicAdd(lossAcc, ls);
}

__global__ void vq_fin(const float* __restrict__ lossAcc,
                       float* __restrict__ out) {
    // loss = (0.25 + 1.0) * mean((q - z)^2)
    out[NELEM] = 1.25f * lossAcc[0] / (float)NELEM;
}

extern "C" void kernel_launch(void* const* d_in, const int* in_sizes, int n_in,
                              void* d_out, int out_size, void* d_ws, size_t ws_size,
                              hipStream_t stream) {
    const float* z = (const float*)d_in[0];
    const float* E = (const float*)d_in[1];
    float* out = (float*)d_out;

    unsigned short* Eb   = (unsigned short*)d_ws;                    // 128 KB
    float* bias          = (float*)((char*)d_ws + 131072);           // 4 KB
    float* lossAcc       = (float*)((char*)d_ws + 131072 + 4096);    // 4 B

    vq_prep<<<4, 256, 0, stream>>>(E, Eb, bias, lossAcc);
    vq_main<<<2048, 256, 0, stream>>>(z, E, Eb, bias, out, lossAcc);
    vq_fin<<<1, 1, 0, stream>>>(lossAcc, out);
}

// Round 2
// 60.965 us; speedup vs baseline: 3.5758x; 3.5758x over previous
//
#include <hip/hip_runtime.h>
#include <hip/hip_bf16.h>

#define CDIM   64
#define HWDIM  4096
#define NCODES 1024
#define NELEM  8388608   // 32*64*64*64 = N*C
#define NBLOCK 512       // vq_main grid: 131072 rows / 256 rows-per-block

typedef short bf16x8 __attribute__((ext_vector_type(8)));
typedef float f32x4  __attribute__((ext_vector_type(4)));

__device__ __forceinline__ unsigned short f2bf(float f) {
    union { float f; unsigned u; } v; v.f = f;
    unsigned r = v.u + 0x7fffu + ((v.u >> 16) & 1u);   // round-to-nearest-even
    return (unsigned short)(r >> 16);
}

// Precompute bf16 codebook + ||e_k||^2 bias.
__global__ void vq_prep(const float* __restrict__ E,
                        unsigned short* __restrict__ Eb,
                        float* __restrict__ bias) {
    int t = blockIdx.x * blockDim.x + threadIdx.x;   // one thread per code
    if (t < NCODES) {
        float s = 0.f;
        #pragma unroll 8
        for (int c = 0; c < CDIM; ++c) {
            float v = E[t * CDIM + c];
            Eb[t * CDIM + c] = f2bf(v);
            s += v * v;
        }
        bias[t] = s;
    }
}

// One wave = 64 rows (4 MFMA row-tiles) x all 1024 codes.
// Block = 4 waves = 256 rows. No global atomics: per-block partial to d_ws.
__global__ __launch_bounds__(256)
void vq_main(const float* __restrict__ z,
             const float* __restrict__ E,
             const unsigned short* __restrict__ Eb,
             const float* __restrict__ bias,
             float* __restrict__ out,
             float* __restrict__ partial) {
    const int lane = threadIdx.x & 63;
    const int wave = threadIdx.x >> 6;
    const int lrow = lane & 15;    // row/code-col within 16-tile
    const int lgrp = lane >> 4;    // k-group 0..3

    const int n0 = blockIdx.x * 256 + wave * 64;  // wave's first flat row
    const int b  = n0 >> 12;
    const int hw = n0 & 4095;                      // 64-aligned; +63 stays in batch
    const float* zb   = z   + (size_t)b * (CDIM * HWDIM);
    float*       outb = out + (size_t)b * (CDIM * HWDIM);

    // A fragments: tile t rows n0+16t..+15. lane holds A[lrow][k=32s+8g+j].
    float szz = 0.f;
    bf16x8 afrag[4][2];
    #pragma unroll
    for (int t = 0; t < 4; ++t)
        #pragma unroll
        for (int s = 0; s < 2; ++s)
            #pragma unroll
            for (int j = 0; j < 8; ++j) {
                int c = 32 * s + 8 * lgrp + j;
                float v = zb[c * HWDIM + hw + t * 16 + lrow];
                szz = fmaf(v, v, szz);
                afrag[t][s][j] = (short)f2bf(v);
            }

    float runmin[4][4];
    int   runidx[4][4];
    #pragma unroll
    for (int t = 0; t < 4; ++t)
        #pragma unroll
        for (int r = 0; r < 4; ++r) { runmin[t][r] = 1e38f; runidx[t][r] = 0; }

    // depth-2 software prefetch of B fragments (static register names, no
    // runtime-indexed register arrays)
    bf16x8 cb0A, cb1A, cb0B, cb1B;
    float  bvA, bvB;
    {
        int c0 = lrow;            // kt=0
        int c1 = 16 + lrow;       // kt=1
        cb0A = *(const bf16x8*)(Eb + c0 * CDIM      + 8 * lgrp);
        cb1A = *(const bf16x8*)(Eb + c0 * CDIM + 32 + 8 * lgrp);
        cb0B = *(const bf16x8*)(Eb + c1 * CDIM      + 8 * lgrp);
        cb1B = *(const bf16x8*)(Eb + c1 * CDIM + 32 + 8 * lgrp);
        bvA = bias[c0];
        bvB = bias[c1];
    }

    for (int kt = 0; kt < 64; kt += 2) {
        // even step
        {
            bf16x8 b0 = cb0A, b1 = cb1A; float bv = bvA;
            if (kt + 2 < 64) {
                int code = (kt + 2) * 16 + lrow;
                cb0A = *(const bf16x8*)(Eb + code * CDIM      + 8 * lgrp);
                cb1A = *(const bf16x8*)(Eb + code * CDIM + 32 + 8 * lgrp);
                bvA  = bias[code];
            }
            const int code = kt * 16 + lrow;
            #pragma unroll
            for (int t = 0; t < 4; ++t) {
                f32x4 acc = {0.f, 0.f, 0.f, 0.f};
                acc = __builtin_amdgcn_mfma_f32_16x16x32_bf16(afrag[t][0], b0, acc, 0, 0, 0);
                acc = __builtin_amdgcn_mfma_f32_16x16x32_bf16(afrag[t][1], b1, acc, 0, 0, 0);
                #pragma unroll
                for (int r = 0; r < 4; ++r) {
                    float d = fmaf(acc[r], -2.f, bv);   // ||e||^2 - 2 z.e
                    if (d < runmin[t][r]) { runmin[t][r] = d; runidx[t][r] = code; }
                }
            }
        }
        // odd step
        {
            bf16x8 b0 = cb0B, b1 = cb1B; float bv = bvB;
            if (kt + 3 < 64) {
                int code = (kt + 3) * 16 + lrow;
                cb0B = *(const bf16x8*)(Eb + code * CDIM      + 8 * lgrp);
                cb1B = *(const bf16x8*)(Eb + code * CDIM + 32 + 8 * lgrp);
                bvB  = bias[code];
            }
            const int code = (kt + 1) * 16 + lrow;
            #pragma unroll
            for (int t = 0; t < 4; ++t) {
                f32x4 acc = {0.f, 0.f, 0.f, 0.f};
                acc = __builtin_amdgcn_mfma_f32_16x16x32_bf16(afrag[t][0], b0, acc, 0, 0, 0);
                acc = __builtin_amdgcn_mfma_f32_16x16x32_bf16(afrag[t][1], b1, acc, 0, 0, 0);
                #pragma unroll
                for (int r = 0; r < 4; ++r) {
                    float d = fmaf(acc[r], -2.f, bv);
                    if (d < runmin[t][r]) { runmin[t][r] = d; runidx[t][r] = code; }
                }
            }
        }
    }

    // reduce (min, idx) across the 16 code-columns (lrow lanes)
    #pragma unroll
    for (int m = 1; m <= 8; m <<= 1) {
        #pragma unroll
        for (int t = 0; t < 4; ++t)
            #pragma unroll
            for (int r = 0; r < 4; ++r) {
                float om = __shfl_xor(runmin[t][r], m, 64);
                int   oi = __shfl_xor(runidx[t][r], m, 64);
                if (om < runmin[t][r] || (om == runmin[t][r] && oi < runidx[t][r])) {
                    runmin[t][r] = om; runidx[t][r] = oi;
                }
            }
    }

    // publish per-row argmin: lane group g holds rows 4g+r of each tile
    __shared__ int   sidx[4][64];
    __shared__ float lpart[4];
    if (lrow == 0) {
        #pragma unroll
        for (int t = 0; t < 4; ++t)
            #pragma unroll
            for (int r = 0; r < 4; ++r)
                sidx[wave][t * 16 + 4 * lgrp + r] = runidx[t][r];
    }

    // loss partial: sum(z^2) + sum over rows of d_min  (== sum (q-z)^2)
    float dsum = 0.f;
    #pragma unroll
    for (int t = 0; t < 4; ++t)
        #pragma unroll
        for (int r = 0; r < 4; ++r) dsum += runmin[t][r];
    float contrib = szz + ((lrow == 0) ? dsum : 0.f);
    #pragma unroll
    for (int m = 32; m >= 1; m >>= 1) contrib += __shfl_xor(contrib, m, 64);
    if (lane == 0) lpart[wave] = contrib;
    __syncthreads();

    // epilogue: gather fp32 codebook rows, write transposed out
    #pragma unroll
    for (int t = 0; t < 4; ++t) {
        const int idxr = sidx[wave][t * 16 + lrow];
        const f32x4* ep  = (const f32x4*)(E + idxr * CDIM      + 8 * lgrp);
        const f32x4* ep2 = (const f32x4*)(E + idxr * CDIM + 32 + 8 * lgrp);
        f32x4 qa = ep[0], qb = ep[1], qc = ep2[0], qd = ep2[1];
        float* ob = outb + hw + t * 16 + lrow;
        #pragma unroll
        for (int j = 0; j < 4; ++j) {
            ob[(8 * lgrp + j)      * HWDIM] = qa[j];
            ob[(8 * lgrp + 4 + j)  * HWDIM] = qb[j];
            ob[(32 + 8 * lgrp + j)     * HWDIM] = qc[j];
            ob[(32 + 8 * lgrp + 4 + j) * HWDIM] = qd[j];
        }
    }

    if (threadIdx.x == 0)
        partial[blockIdx.x] = lpart[0] + lpart[1] + lpart[2] + lpart[3];
}

__global__ void vq_fin(const float* __restrict__ partial,
                       float* __restrict__ out) {
    int lane = threadIdx.x;
    float s = 0.f;
    for (int i = lane; i < NBLOCK; i += 64) s += partial[i];
    #pragma unroll
    for (int m = 32; m >= 1; m >>= 1) s += __shfl_xor(s, m, 64);
    if (lane == 0) out[NELEM] = 1.25f * s / (float)NELEM;
}

extern "C" void kernel_launch(void* const* d_in, const int* in_sizes, int n_in,
                              void* d_out, int out_size, void* d_ws, size_t ws_size,
                              hipStream_t stream) {
    const float* z = (const float*)d_in[0];
    const float* E = (const float*)d_in[1];
    float* out = (float*)d_out;

    unsigned short* Eb = (unsigned short*)d_ws;                    // 128 KB
    float* bias        = (float*)((char*)d_ws + 131072);           // 4 KB
    float* partial     = (float*)((char*)d_ws + 131072 + 4096);    // 2 KB

    vq_prep<<<4, 256, 0, stream>>>(E, Eb, bias);
    vq_main<<<NBLOCK, 256, 0, stream>>>(z, E, Eb, bias, out, partial);
    vq_fin<<<1, 64, 0, stream>>>(partial, out);
}